// Round 1
// baseline (777.622 us; speedup 1.0000x reference)
//
#include <hip/hip_runtime.h>

#define NB 8
#define NC 64
#define NN 4096
#define NO 64
#define KK 20
#define EPSV 1e-5f
#define SLOPE 0.2f

// ws layout (float units):
// y1 : [B][N][O]   off 0         (2097152)
// y2 : [B][N][O]   off 2097152
// xx : [B][N]      off 4194304   (32768)
// idx: [B][N][K]   off 4227072   (655360 ints)
// wa : [C][O]      off 4882432   (4096)
// wb : [C][O]      off 4886528   (4096)
// total 4890624 floats = 19.6 MB

__global__ void k0_wprep(const float* __restrict__ W,
                         float* __restrict__ wa, float* __restrict__ wb) {
  int t = threadIdx.x;
  for (int i = t; i < NC * NO; i += 256) {
    int o = i & 63, c = i >> 6;
    float w1 = W[o * 128 + c];
    float w2 = W[o * 128 + 64 + c];
    wa[i] = w1 - w2;  // [c][o]
    wb[i] = w2;
  }
}

__global__ __launch_bounds__(256) void k1_feat(const float* __restrict__ x,
    const float* __restrict__ waT, const float* __restrict__ wbT,
    float* __restrict__ y1, float* __restrict__ y2, float* __restrict__ xxg) {
  __shared__ __align__(16) float xs[NC * 64];   // [c][n]
  __shared__ __align__(16) float wa[NC * NO];   // [c][o]
  __shared__ __align__(16) float wb[NC * NO];
  int t = threadIdx.x;
  int b = blockIdx.x >> 6;
  int gr0 = (blockIdx.x & 63) << 6;
  const float* xb = x + (size_t)b * NC * NN;
  #pragma unroll
  for (int k = 0; k < 4; ++k) {
    int i4 = t + k * 256;            // 0..1023
    int c = i4 >> 4, col4 = (i4 & 15) << 2;
    *(float4*)&xs[c * 64 + col4] = *(const float4*)&xb[(size_t)c * NN + gr0 + col4];
    *(float4*)&wa[c * 64 + col4] = *(const float4*)&waT[c * 64 + col4];
    *(float4*)&wb[c * 64 + col4] = *(const float4*)&wbT[c * 64 + col4];
  }
  __syncthreads();
  if (t < 64) {
    float s = 0.f;
    #pragma unroll
    for (int c = 0; c < NC; ++c) { float v = xs[c * 64 + t]; s = fmaf(v, v, s); }
    xxg[b * NN + gr0 + t] = s;
  }
  int o = t & 63, w = t >> 6;
  for (int j = 0; j < 16; ++j) {
    int n = j * 4 + w;
    float a1 = 0.f, a2 = 0.f;
    #pragma unroll
    for (int c = 0; c < NC; ++c) {
      float xv = xs[c * 64 + n];               // wave-uniform broadcast
      a1 = fmaf(wa[c * 64 + o], xv, a1);
      a2 = fmaf(wb[c * 64 + o], xv, a2);
    }
    size_t base = ((size_t)b * NN + gr0 + n) * NO + o;
    y1[base] = a1;
    y2[base] = a2;
  }
}

// ----- fused Gram + per-row top-K -----
__global__ __launch_bounds__(256) void k2_topk(const float* __restrict__ x,
    const float* __restrict__ xxg, int* __restrict__ idxg) {
  __shared__ __align__(16) float smem[12608];  // 49.25 KB
  float* As = smem;                   // [c][r]  4096
  float* Bs = smem + 4096;            // [c][m]  4096
  float* xxs = smem + 8192;           // 64
  unsigned* cand = (unsigned*)(smem + 8256);  // [m][r], row stride 68 (pad: conflict-free scan)

  int t = threadIdx.x;
  int b = blockIdx.x >> 6;
  int gr0 = (blockIdx.x & 63) << 6;
  const float* xb = x + (size_t)b * NC * NN;
  int ty = t >> 4, tx = t & 15;       // 4x4 register tile: rows 4ty.., cols 4tx..
  int orow = t & 63, oq = t >> 6;     // owner: row, quarter

  // stage A-tile once (rows of this block)
  #pragma unroll
  for (int k = 0; k < 4; ++k) {
    int i4 = t + k * 256;
    int c = i4 >> 4, col4 = (i4 & 15) << 2;
    *(float4*)&As[c * 64 + col4] = *(const float4*)&xb[(size_t)c * NN + gr0 + col4];
  }

  unsigned kv[KK];
  int ki[KK];
  #pragma unroll
  for (int j = 0; j < KK; ++j) { kv[j] = 0xFFFFFFFFu; ki[j] = 0; }

  for (int mt = 0; mt < 64; ++mt) {
    int gm0 = mt << 6;
    __syncthreads();  // protect Bs/cand from previous tile's readers (also covers A at mt=0)
    #pragma unroll
    for (int k = 0; k < 4; ++k) {
      int i4 = t + k * 256;
      int c = i4 >> 4, col4 = (i4 & 15) << 2;
      *(float4*)&Bs[c * 64 + col4] = *(const float4*)&xb[(size_t)c * NN + gm0 + col4];
    }
    if (t < 16) *(float4*)&xxs[t * 4] = *(const float4*)&xxg[b * NN + gm0 + t * 4];
    __syncthreads();

    float acc[4][4];
    #pragma unroll
    for (int i = 0; i < 4; ++i)
      #pragma unroll
      for (int j = 0; j < 4; ++j) acc[i][j] = 0.f;

    #pragma unroll 8
    for (int c = 0; c < 64; ++c) {
      float4 av = *(const float4*)&As[c * 64 + ty * 4];
      float4 bv = *(const float4*)&Bs[c * 64 + tx * 4];
      float a_[4] = {av.x, av.y, av.z, av.w};
      float b_[4] = {bv.x, bv.y, bv.z, bv.w};
      #pragma unroll
      for (int i = 0; i < 4; ++i)
        #pragma unroll
        for (int j = 0; j < 4; ++j)
          acc[i][j] = fmaf(a_[i], b_[j], acc[i][j]);
    }

    // keys: xx[m] - 2*G (row-constant xx[r] dropped; ordering identical). flip to sortable uint.
    float4 xxv = *(const float4*)&xxs[tx * 4];
    float xq[4] = {xxv.x, xxv.y, xxv.z, xxv.w};
    #pragma unroll
    for (int j = 0; j < 4; ++j) {
      uint4 kw;
      unsigned* kwp = (unsigned*)&kw;
      #pragma unroll
      for (int i = 0; i < 4; ++i) {
        float keyf = xq[j] - 2.f * acc[i][j];
        unsigned u = __float_as_uint(keyf);
        kwp[i] = (u & 0x80000000u) ? ~u : (u | 0x80000000u);
      }
      *(uint4*)&cand[(tx * 4 + j) * 68 + ty * 4] = kw;  // [m][r], 16B aligned
    }
    __syncthreads();

    // scan: thread owns (row, quarter) -> 16 candidates, conflict-free lane-consecutive reads
    #pragma unroll 1
    for (int i = 0; i < 16; ++i) {
      unsigned v = cand[(oq * 16 + i) * 68 + orow];
      if (v < kv[KK - 1]) {
        int m = gm0 + oq * 16 + i;
        #pragma unroll
        for (int j = KK - 1; j >= 1; --j) {
          unsigned pv = kv[j - 1];
          int pi = ki[j - 1];
          bool sh = v < pv;
          bool pl = v < kv[j];
          kv[j] = sh ? pv : (pl ? v : kv[j]);
          ki[j] = sh ? pi : (pl ? m : ki[j]);
        }
        if (v < kv[0]) { kv[0] = v; ki[0] = m; }
      }
    }
  }

  // merge 4 per-quarter sorted lists per row
  __syncthreads();
  unsigned* mv = (unsigned*)smem;         // [r][q][k], row stride 81 (odd: conflict-free)
  int* mi = (int*)(smem + 5184);
  #pragma unroll
  for (int k = 0; k < KK; ++k) {
    mv[orow * 81 + oq * 20 + k] = kv[k];
    mi[orow * 81 + oq * 20 + k] = ki[k];
  }
  __syncthreads();
  if (t < 64) {
    int h0 = 0, h1 = 0, h2 = 0, h3 = 0;
    int rb = t * 81;
    int* op = idxg + ((size_t)b * NN + gr0 + t) * KK;
    for (int k = 0; k < KK; ++k) {
      unsigned v0 = mv[rb + 0 * 20 + h0];
      unsigned v1 = mv[rb + 1 * 20 + h1];
      unsigned v2 = mv[rb + 2 * 20 + h2];
      unsigned v3 = mv[rb + 3 * 20 + h3];
      unsigned bv = v0; int bq = 0, bh = h0;
      if (v1 < bv) { bv = v1; bq = 1; bh = h1; }
      if (v2 < bv) { bv = v2; bq = 2; bh = h2; }
      if (v3 < bv) { bv = v3; bq = 3; bh = h3; }
      op[k] = mi[rb + bq * 20 + bh];
      if (bq == 0) h0++; else if (bq == 1) h1++; else if (bq == 2) h2++; else h3++;
    }
  }
}

__global__ __launch_bounds__(256) void k3_out(const float* __restrict__ y1,
    const float* __restrict__ y2, const int* __restrict__ idxg,
    const float* __restrict__ gamma, const float* __restrict__ beta,
    const float* __restrict__ rmean, const float* __restrict__ rvar,
    float* __restrict__ out) {
  __shared__ int sidx[64 * KK];
  __shared__ float ot[64 * 65];  // [o][n], pad 65
  int t = threadIdx.x;
  int b = blockIdx.x >> 6;
  int gr0 = (blockIdx.x & 63) << 6;
  const int* ib = idxg + ((size_t)b * NN + gr0) * KK;
  for (int i = t; i < 64 * KK; i += 256) sidx[i] = ib[i];
  int l = t & 63, w = t >> 6;
  float sc = gamma[l] * rsqrtf(rvar[l] + EPSV);
  float tt = fmaf(-rmean[l], sc, beta[l]);
  __syncthreads();
  const float* y2b = y2 + (size_t)b * NN * NO;
  for (int rr = 0; rr < 16; ++rr) {
    int row = w * 16 + rr;
    float v1 = y1[((size_t)b * NN + gr0 + row) * NO + l];
    float best = -3.4e38f;
    #pragma unroll 4
    for (int k = 0; k < KK; ++k) {
      int m = sidx[row * KK + k];                 // wave-uniform broadcast
      float v = v1 + y2b[(size_t)m * NO + l];     // coalesced 256B gather
      v = fmaf(v, sc, tt);
      v = v >= 0.f ? v : SLOPE * v;
      best = fmaxf(best, v);
    }
    ot[l * 65 + row] = best;
  }
  __syncthreads();
  float* ob = out + (size_t)b * NO * NN;
  for (int i = t; i < 4096; i += 256) {
    int o = i >> 6, n = i & 63;
    ob[(size_t)o * NN + gr0 + n] = ot[o * 65 + n];  // coalesced
  }
}

extern "C" void kernel_launch(void* const* d_in, const int* in_sizes, int n_in,
                              void* d_out, int out_size, void* d_ws, size_t ws_size,
                              hipStream_t stream) {
  const float* x     = (const float*)d_in[0];
  const float* W     = (const float*)d_in[1];
  const float* gamma = (const float*)d_in[2];
  const float* beta  = (const float*)d_in[3];
  const float* rmean = (const float*)d_in[4];
  const float* rvar  = (const float*)d_in[5];
  float* ws  = (float*)d_ws;
  float* y1  = ws;
  float* y2  = ws + 2097152;
  float* xx  = ws + 4194304;
  int*   idx = (int*)(ws + 4227072);
  float* wa  = ws + 4882432;
  float* wb  = ws + 4886528;
  float* out = (float*)d_out;

  hipLaunchKernelGGL(k0_wprep, dim3(1),   dim3(256), 0, stream, W, wa, wb);
  hipLaunchKernelGGL(k1_feat,  dim3(512), dim3(256), 0, stream, x, wa, wb, y1, y2, xx);
  hipLaunchKernelGGL(k2_topk,  dim3(512), dim3(256), 0, stream, x, xx, idx);
  hipLaunchKernelGGL(k3_out,   dim3(512), dim3(256), 0, stream, y1, y2, idx,
                     gamma, beta, rmean, rvar, out);
}